// Round 14
// baseline (265.713 us; speedup 1.0000x reference)
//
#include <hip/hip_runtime.h>
#include <math.h>

#define WF 64

__device__ __forceinline__ float silu_f(float v){ return v / (1.0f + expf(-v)); }

typedef __attribute__((ext_vector_type(8))) short bf16x8;
typedef __attribute__((ext_vector_type(4))) float f32x4;

// ---------- CSR build ----------
__global__ __launch_bounds__(256) void k_count(const int* __restrict__ dst, int* __restrict__ cnt, int E){
  int e = blockIdx.x*blockDim.x + threadIdx.x;
  if (e < E) atomicAdd(&cnt[dst[e]], 1);
}

// block-local exclusive scan over chunks of 2048 (256 thr x 8 items)
__global__ __launch_bounds__(256) void k_scan1(const int* __restrict__ cnt, int* __restrict__ rowstart, int* __restrict__ bsum, int N){
  __shared__ int s[256];
  int tid = threadIdx.x;
  int base = blockIdx.x*2048 + tid*8;
  int loc[8]; int tsum = 0;
#pragma unroll
  for (int j=0;j<8;++j){ int idx=base+j; int v = (idx<N)?cnt[idx]:0; loc[j]=tsum; tsum+=v; }
  s[tid]=tsum; __syncthreads();
  for (int off=1; off<256; off<<=1){
    int v = (tid>=off)? s[tid-off] : 0;
    __syncthreads();
    s[tid] += v;
    __syncthreads();
  }
  int texc = s[tid] - tsum;
  if (tid==255) bsum[blockIdx.x] = s[255];
#pragma unroll
  for (int j=0;j<8;++j){ int idx=base+j; if (idx<N) rowstart[idx] = texc + loc[j]; }
}

// scan3: adds block prefix (from bsum), writes cursor/dinv and dxp = {di, di*x}
__global__ __launch_bounds__(256) void k_scan3(const int* __restrict__ bsum, const int* __restrict__ cnt,
                        const float* __restrict__ x,
                        int* __restrict__ rowstart, int* __restrict__ cursor,
                        float* __restrict__ dinv, float4* __restrict__ dxp,
                        int N, int E, int nb){
  __shared__ int boffs;
  int tid = threadIdx.x;
  int b = (blockIdx.x*blockDim.x) >> 11;   // uniform within block (256 <= 2048)
  if (tid < WF){
    int v = (tid < nb && tid < b) ? bsum[tid] : 0;
#pragma unroll
    for (int off=32; off; off>>=1) v += __shfl_down(v, off);
    if (tid==0) boffs = v;
  }
  __syncthreads();
  int idx = blockIdx.x*blockDim.x + tid;
  if (idx < N){
    int v = rowstart[idx] + boffs;
    rowstart[idx]=v; cursor[idx]=v;
    float di = rsqrtf((float)(cnt[idx]+1));   // +1 self-loop
    dinv[idx] = di;
    float4 o;
    o.x = di;
    o.y = di*x[3*idx+0];
    o.z = di*x[3*idx+1];
    o.w = di*x[3*idx+2];
    dxp[idx] = o;
  }
  if (idx==0) rowstart[N]=E;
}

// fill CSR: minimum scatter — one 4B colsrc write + cursor atomic per edge
__global__ __launch_bounds__(256) void k_fill(const int* __restrict__ src, const int* __restrict__ dst,
                       int* __restrict__ cursor, int* __restrict__ colsrc, int E){
  int e = blockIdx.x*blockDim.x + threadIdx.x;
  if (e < E){
    int d = dst[e];
    int pos = atomicAdd(&cursor[d], 1);
    colsrc[pos] = src[e];
  }
}

// ---------- layer 1: CSR walk over dxp (16B gathers, 4x unroll), then @W1+b1, silu ----------
__global__ __launch_bounds__(256) void k_l1(const float4* __restrict__ dxp,
                     const int* __restrict__ rowstart, const int* __restrict__ colsrc,
                     const float* __restrict__ W1, const float* __restrict__ b1,
                     float* __restrict__ h1s, int N){
  __shared__ float w[300];
  __shared__ float bb[100];
  int tid = threadIdx.x;
  for (int t=tid; t<300; t+=blockDim.x) w[t]=W1[t];
  for (int t=tid; t<100; t+=blockDim.x) bb[t]=b1[t];
  __syncthreads();
  int i = blockIdx.x*blockDim.x + tid;
  if (i >= N) return;
  float4 self = dxp[i];
  float di = self.x;
  float sx = self.y, sy = self.z, sz = self.w;
  int jb = rowstart[i], je = rowstart[i+1];
  int j = jb;
  for (; j+3 < je; j += 4){
    float4 r0 = dxp[colsrc[j]];
    float4 r1 = dxp[colsrc[j+1]];
    float4 r2 = dxp[colsrc[j+2]];
    float4 r3 = dxp[colsrc[j+3]];
    sx += (r0.y + r1.y) + (r2.y + r3.y);
    sy += (r0.z + r1.z) + (r2.z + r3.z);
    sz += (r0.w + r1.w) + (r2.w + r3.w);
  }
  for (; j < je; ++j){
    float4 r = dxp[colsrc[j]];
    sx += r.y; sy += r.z; sz += r.w;
  }
  sx*=di; sy*=di; sz*=di;
  float* orow = h1s + (size_t)i*100;
#pragma unroll
  for (int f0=0; f0<100; f0+=4){
    float4 o;
    o.x = silu_f(sx*w[f0+0] + sy*w[100+f0+0] + sz*w[200+f0+0] + bb[f0+0]);
    o.y = silu_f(sx*w[f0+1] + sy*w[100+f0+1] + sz*w[200+f0+1] + bb[f0+1]);
    o.z = silu_f(sx*w[f0+2] + sy*w[100+f0+2] + sz*w[200+f0+2] + bb[f0+2]);
    o.w = silu_f(sx*w[f0+3] + sy*w[100+f0+3] + sz*w[200+f0+3] + bb[f0+3]);
    *(float4*)&orow[f0] = o;
  }
}

// ---------- layer 2 aggregation: a2 = A_norm h1s  (100 feats) ----------
// HALF-WAVE per node: 32-lane group, lanes 0..24 own 4 feats via one float4
// gather (400B = exact row) per neighbor. 8 nodes per 256-thr block.
__global__ __launch_bounds__(256) void k_agg2(const float* __restrict__ h1s, const int* __restrict__ rowstart,
                       const int* __restrict__ colsrc, const float* __restrict__ dinv,
                       float* __restrict__ a2, int N){
  int node = blockIdx.x*8 + (threadIdx.x >> 5);
  int lane = threadIdx.x & 31;
  if (node >= N) return;
  bool act = lane < 25;
  float di = dinv[node];
  float4 acc = make_float4(0.f,0.f,0.f,0.f);
  if (act){
    float4 v = *(const float4*)(h1s + (size_t)node*100 + lane*4);
    acc.x = di*v.x; acc.y = di*v.y; acc.z = di*v.z; acc.w = di*v.w;
  }
  int jb = rowstart[node], je = rowstart[node+1];
  int j = jb;
  for (; j+1 < je; j += 2){
    int u0 = colsrc[j];   float w0 = dinv[u0];
    int u1 = colsrc[j+1]; float w1 = dinv[u1];
    if (act){
      float4 r0 = *(const float4*)(h1s + (size_t)u0*100 + lane*4);
      float4 r1 = *(const float4*)(h1s + (size_t)u1*100 + lane*4);
      acc.x += w0*r0.x + w1*r1.x;
      acc.y += w0*r0.y + w1*r1.y;
      acc.z += w0*r0.z + w1*r1.z;
      acc.w += w0*r0.w + w1*r1.w;
    }
  }
  if (j < je){
    int u = colsrc[j]; float wv = dinv[u];
    if (act){
      float4 r = *(const float4*)(h1s + (size_t)u*100 + lane*4);
      acc.x += wv*r.x; acc.y += wv*r.y; acc.z += wv*r.z; acc.w += wv*r.w;
    }
  }
  if (act){
    float4 o;
    o.x = di*acc.x; o.y = di*acc.y; o.z = di*acc.z; o.w = di*acc.w;
    *(float4*)(a2 + (size_t)node*100 + lane*4) = o;
  }
}

// ---------- layer 2 matmul via split-bf16 MFMA + fused mean-pool ----------
// h2 = silu(a2 @ W2 + b2). a = a_hi + a_lo (bf16); compute hi*hi + hi*lo + lo*hi
// with mfma_f32_16x16x32_bf16 (missing lo*lo term ~2^-16 relative — way under
// threshold). Block 256 thr = 4 waves; tile 64n x 32f; wave w: nodes
// [n0+w*16, +16), two 16-f MFMA tiles. K padded 100->128 (zero), 4 k-steps.
// NOTE: k-permutation inside fragments cancels (A and W staged with identical
// k-indexing; MFMA contracts slot-wise). C/D map: col=lane&15,
// row=(lane>>4)*4+reg  [HW-verified]. Epilogue: silu -> LDS pooled window.
#define AST 136   // k-stride in ushorts: 272B rows -> 16B-aligned frags, 2-way-free banks
__global__ __launch_bounds__(256) void k_mm2(const float* __restrict__ a2, const float* __restrict__ W2,
                      const float* __restrict__ b2, const int* __restrict__ batch,
                      float* __restrict__ pooled, int N){
  __shared__ unsigned short aH[64*AST];
  __shared__ unsigned short aL[64*AST];
  __shared__ unsigned short wH[32*AST];
  __shared__ unsigned short wL[32*AST];
  int tid = threadIdx.x;
  int l = tid & 63, w = tid >> 6;
  int n0 = blockIdx.x * 64;
  int fb = blockIdx.y;              // f-base = fb*32

  // ---- stage W tile [32f][128k] hi/lo (zero-pad k>=100, f>=200) ----
  for (int idx = tid; idx < 4096; idx += 256){
    int f = idx & 31, k = idx >> 5;           // f contiguous -> coalesced 128B
    int gf = fb*32 + f;
    float v = (k < 100 && gf < 200) ? W2[(size_t)k*200 + gf] : 0.f;
    unsigned int b = __float_as_uint(v);
    unsigned int h = (b + 0x8000u) >> 16;
    float hf = __uint_as_float(h << 16);
    float lo = v - hf;
    unsigned int bl = __float_as_uint(lo);
    unsigned int hl = (bl + 0x8000u) >> 16;
    wH[f*AST + k] = (unsigned short)h;
    wL[f*AST + k] = (unsigned short)hl;
  }
  // ---- stage A tile [64n][128k] hi/lo ----
  for (int idx = tid; idx < 8192; idx += 256){
    int n = idx >> 7, k = idx & 127;          // k contiguous -> coalesced
    int gn = n0 + n;
    float v = (k < 100 && gn < N) ? a2[(size_t)gn*100 + k] : 0.f;
    unsigned int b = __float_as_uint(v);
    unsigned int h = (b + 0x8000u) >> 16;
    float hf = __uint_as_float(h << 16);
    float lo = v - hf;
    unsigned int bl = __float_as_uint(lo);
    unsigned int hl = (bl + 0x8000u) >> 16;
    aH[n*AST + k] = (unsigned short)h;
    aL[n*AST + k] = (unsigned short)hl;
  }
  __syncthreads();

  // ---- MFMA: 4 k-steps x (2 f-tiles x 3 mfma) ----
  f32x4 acc0 = {0.f,0.f,0.f,0.f};
  f32x4 acc1 = {0.f,0.f,0.f,0.f};
  int row = l & 15;     // A-row within wave tile / B-col within f-tile
  int kg  = l >> 4;     // k-group 0..3 (8 k each)
#pragma unroll
  for (int ks = 0; ks < 4; ++ks){
    int ko = ks*32 + kg*8;
    int ao  = (w*16 + row)*AST + ko;
    bf16x8 ah = *(const bf16x8*)&aH[ao];
    bf16x8 al = *(const bf16x8*)&aL[ao];
    int wo0 = row*AST + ko;
    int wo1 = (16 + row)*AST + ko;
    bf16x8 wh0 = *(const bf16x8*)&wH[wo0];
    bf16x8 wl0 = *(const bf16x8*)&wL[wo0];
    bf16x8 wh1 = *(const bf16x8*)&wH[wo1];
    bf16x8 wl1 = *(const bf16x8*)&wL[wo1];
    acc0 = __builtin_amdgcn_mfma_f32_16x16x32_bf16(ah, wh0, acc0, 0, 0, 0);
    acc0 = __builtin_amdgcn_mfma_f32_16x16x32_bf16(ah, wl0, acc0, 0, 0, 0);
    acc0 = __builtin_amdgcn_mfma_f32_16x16x32_bf16(al, wh0, acc0, 0, 0, 0);
    acc1 = __builtin_amdgcn_mfma_f32_16x16x32_bf16(ah, wh1, acc1, 0, 0, 0);
    acc1 = __builtin_amdgcn_mfma_f32_16x16x32_bf16(ah, wl1, acc1, 0, 0, 0);
    acc1 = __builtin_amdgcn_mfma_f32_16x16x32_bf16(al, wh1, acc1, 0, 0, 0);
  }

  // ---- epilogue: silu + per-block LDS pooled accumulation (8-graph window) ----
  float* plL = (float*)aH;          // [8 graphs][32 f] = 256 floats
  __syncthreads();
  if (tid < 256) plL[tid] = 0.f;
  __syncthreads();

  int g0 = batch[n0];
#pragma unroll
  for (int ft = 0; ft < 2; ++ft){
    f32x4 a = ft ? acc1 : acc0;
    int fl = ft*16 + row;           // local f in [0,32)
    int gf = fb*32 + fl;
    if (gf < 200){
      float bias = b2[gf];
      float s = 0.f;
      int gprev = -1;
#pragma unroll
      for (int r = 0; r < 4; ++r){
        int node = n0 + w*16 + kg*4 + r;   // C/D row = (l>>4)*4 + r
        if (node < N){
          int g = batch[node];
          if (g != gprev){
            if (gprev >= 0){
              int dg = gprev - g0;
              if (dg < 8) atomicAdd(&plL[dg*32 + fl], s);
              else        atomicAdd(&pooled[(size_t)gprev*200 + gf], s);
            }
            gprev = g; s = 0.f;
          }
          s += silu_f(a[r] + bias);
        }
      }
      if (gprev >= 0){
        int dg = gprev - g0;
        if (dg < 8) atomicAdd(&plL[dg*32 + fl], s);
        else        atomicAdd(&pooled[(size_t)gprev*200 + gf], s);
      }
    }
  }
  __syncthreads();
  if (tid < 256){
    float v = plL[tid];
    if (v != 0.f){
      int r = tid >> 5, f = tid & 31;
      int gf = fb*32 + f;
      if (gf < 200) atomicAdd(&pooled[(size_t)(g0+r)*200 + gf], v);
    }
  }
}

// ---------- head: mean finalize + MLP, one block per graph ----------
__global__ __launch_bounds__(256) void k_head(const float* __restrict__ pooled, const int* __restrict__ batch,
                       const float* __restrict__ W3, const float* __restrict__ b3,
                       const float* __restrict__ W4, const float* __restrict__ b4,
                       float* __restrict__ out, int N){
  __shared__ float pl[200];
  __shared__ float h3[100];
  int g = blockIdx.x; int tid = threadIdx.x;
  // lower_bound(batch, g) and lower_bound(batch, g+1) to get node count
  int lo=0, hi=N;
  while (lo<hi){ int m=(lo+hi)>>1; if (batch[m] < g) lo=m+1; else hi=m; }
  int s = lo;
  hi=N;
  while (lo<hi){ int m=(lo+hi)>>1; if (batch[m] < g+1) lo=m+1; else hi=m; }
  int e = lo;
  float inv = (e>s) ? 1.0f/(float)(e-s) : 0.0f;
  if (tid < 200) pl[tid] = pooled[(size_t)g*200 + tid] * inv;
  __syncthreads();
  if (tid < 100){
    float acc = b3[tid];
    for (int k=0;k<200;++k) acc += pl[k]*W3[k*100+tid];
    h3[tid] = silu_f(acc);
  }
  __syncthreads();
  if (tid < WF){
    float p = 0.f;
    if (tid < 100)      p  = h3[tid]     * W4[tid];
    if (tid + 64 < 100) p += h3[tid+64]  * W4[tid+64];
#pragma unroll
    for (int off=32; off; off>>=1) p += __shfl_down(p, off);
    if (tid==0) out[g] = p + b4[0];
  }
}

extern "C" void kernel_launch(void* const* d_in, const int* in_sizes, int n_in,
                              void* d_out, int out_size, void* d_ws, size_t ws_size,
                              hipStream_t stream){
  const float* x  = (const float*)d_in[0];
  const int*   ei = (const int*)  d_in[1];
  const int* batch= (const int*)  d_in[2];
  const float* W1 = (const float*)d_in[4];
  const float* b1 = (const float*)d_in[5];
  const float* W2 = (const float*)d_in[6];
  const float* b2 = (const float*)d_in[7];
  const float* W3 = (const float*)d_in[8];
  const float* b3 = (const float*)d_in[9];
  const float* W4 = (const float*)d_in[10];
  const float* b4 = (const float*)d_in[11];
  float* out = (float*)d_out;

  int N = in_sizes[0]/3;
  int E = in_sizes[1]/2;
  int G = out_size;
  const int* src = ei;
  const int* dst = ei + E;

  char* base = (char*)d_ws; size_t off = 0;
  auto alloc = [&](size_t bytes)->void*{
    void* p = base + off;
    off = (off + bytes + 255) & ~(size_t)255;
    return p;
  };
  // zero-init group first (single memset): cnt, pooled
  int*   cnt      = (int*)  alloc((size_t)N*4);
  float* pooled   = (float*)alloc((size_t)G*200*4);
  size_t zbytes   = off;
  int*   rowstart = (int*)  alloc((size_t)(N+1)*4);
  int*   cursor   = (int*)  alloc((size_t)N*4);
  int*   bsum     = (int*)  alloc(4096);
  int*   colsrc   = (int*)  alloc((size_t)E*4);
  float* dinv     = (float*)alloc((size_t)N*4);
  float4* dxp     = (float4*)alloc((size_t)N*16);
  float* h1s      = (float*)alloc((size_t)N*100*4);
  float* a2       = (float*)alloc((size_t)N*100*4);
  (void)ws_size; (void)n_in;

  hipMemsetAsync(base, 0, zbytes, stream);
  int gE = (E+255)/256;
  k_count<<<gE,256,0,stream>>>(dst, cnt, E);
  int nb = (N+2047)/2048;
  k_scan1<<<nb,256,0,stream>>>(cnt, rowstart, bsum, N);
  k_scan3<<<(N+255)/256,256,0,stream>>>(bsum, cnt, x, rowstart, cursor, dinv, dxp, N, E, nb);
  k_fill<<<gE,256,0,stream>>>(src, dst, cursor, colsrc, E);
  k_l1<<<(N+255)/256,256,0,stream>>>(dxp, rowstart, colsrc, W1, b1, h1s, N);
  k_agg2<<<(N+7)/8,256,0,stream>>>(h1s, rowstart, colsrc, dinv, a2, N);
  dim3 gmm((N+63)/64, 7);
  k_mm2<<<gmm,256,0,stream>>>(a2, W2, b2, batch, pooled, N);
  k_head<<<G,256,0,stream>>>(pooled, batch, W3, b3, W4, b4, out, N);
}

// Round 15
// 182.433 us; speedup vs baseline: 1.4565x; 1.4565x over previous
//
#include <hip/hip_runtime.h>
#include <math.h>

#define WF 64

__device__ __forceinline__ float silu_f(float v){ return v / (1.0f + expf(-v)); }

typedef __attribute__((ext_vector_type(8))) short bf16x8;
typedef __attribute__((ext_vector_type(4))) float f32x4;

__device__ __forceinline__ void bf16split(float v, unsigned short& h, unsigned short& l){
  unsigned int b = __float_as_uint(v);
  unsigned int hh = (b + 0x8000u) >> 16;
  float hf = __uint_as_float(hh << 16);
  float lo = v - hf;
  unsigned int bl = __float_as_uint(lo);
  h = (unsigned short)hh;
  l = (unsigned short)((bl + 0x8000u) >> 16);
}

// ---------- CSR build ----------
__global__ __launch_bounds__(256) void k_count(const int* __restrict__ dst, int* __restrict__ cnt, int E){
  int e = blockIdx.x*blockDim.x + threadIdx.x;
  if (e < E) atomicAdd(&cnt[dst[e]], 1);
}

// block-local exclusive scan over chunks of 2048 (256 thr x 8 items)
__global__ __launch_bounds__(256) void k_scan1(const int* __restrict__ cnt, int* __restrict__ rowstart, int* __restrict__ bsum, int N){
  __shared__ int s[256];
  int tid = threadIdx.x;
  int base = blockIdx.x*2048 + tid*8;
  int loc[8]; int tsum = 0;
#pragma unroll
  for (int j=0;j<8;++j){ int idx=base+j; int v = (idx<N)?cnt[idx]:0; loc[j]=tsum; tsum+=v; }
  s[tid]=tsum; __syncthreads();
  for (int off=1; off<256; off<<=1){
    int v = (tid>=off)? s[tid-off] : 0;
    __syncthreads();
    s[tid] += v;
    __syncthreads();
  }
  int texc = s[tid] - tsum;
  if (tid==255) bsum[blockIdx.x] = s[255];
#pragma unroll
  for (int j=0;j<8;++j){ int idx=base+j; if (idx<N) rowstart[idx] = texc + loc[j]; }
}

// scan3: adds block prefix (from bsum), writes cursor/dinv and dxp = {di, di*x}
__global__ __launch_bounds__(256) void k_scan3(const int* __restrict__ bsum, const int* __restrict__ cnt,
                        const float* __restrict__ x,
                        int* __restrict__ rowstart, int* __restrict__ cursor,
                        float* __restrict__ dinv, float4* __restrict__ dxp,
                        int N, int E, int nb){
  __shared__ int boffs;
  int tid = threadIdx.x;
  int b = (blockIdx.x*blockDim.x) >> 11;   // uniform within block (256 <= 2048)
  if (tid < WF){
    int v = (tid < nb && tid < b) ? bsum[tid] : 0;
#pragma unroll
    for (int off=32; off; off>>=1) v += __shfl_down(v, off);
    if (tid==0) boffs = v;
  }
  __syncthreads();
  int idx = blockIdx.x*blockDim.x + tid;
  if (idx < N){
    int v = rowstart[idx] + boffs;
    rowstart[idx]=v; cursor[idx]=v;
    float di = rsqrtf((float)(cnt[idx]+1));   // +1 self-loop
    dinv[idx] = di;
    float4 o;
    o.x = di;
    o.y = di*x[3*idx+0];
    o.z = di*x[3*idx+1];
    o.w = di*x[3*idx+2];
    dxp[idx] = o;
  }
  if (idx==0) rowstart[N]=E;
}

// fill CSR: minimum scatter — one 4B colsrc write + cursor atomic per edge
__global__ __launch_bounds__(256) void k_fill(const int* __restrict__ src, const int* __restrict__ dst,
                       int* __restrict__ cursor, int* __restrict__ colsrc, int E){
  int e = blockIdx.x*blockDim.x + threadIdx.x;
  if (e < E){
    int d = dst[e];
    int pos = atomicAdd(&cursor[d], 1);
    colsrc[pos] = src[e];
  }
}

// W2 -> transposed bf16 hi/lo planes [224 f][128 k], zero-padded
__global__ __launch_bounds__(256) void k_wconv(const float* __restrict__ W2,
                       unsigned short* __restrict__ w2th, unsigned short* __restrict__ w2tl){
  int idx = blockIdx.x*blockDim.x + threadIdx.x;
  if (idx < 224*128){
    int f = idx >> 7, k = idx & 127;
    float v = (f < 200 && k < 100) ? W2[(size_t)k*200 + f] : 0.f;
    unsigned short h, l;
    bf16split(v, h, l);
    w2th[idx] = h;
    w2tl[idx] = l;
  }
}

// ---------- layer 1: CSR walk over dxp (16B gathers, 4x unroll), then @W1+b1, silu ----------
__global__ __launch_bounds__(256) void k_l1(const float4* __restrict__ dxp,
                     const int* __restrict__ rowstart, const int* __restrict__ colsrc,
                     const float* __restrict__ W1, const float* __restrict__ b1,
                     float* __restrict__ h1s, int N){
  __shared__ float w[300];
  __shared__ float bb[100];
  int tid = threadIdx.x;
  for (int t=tid; t<300; t+=blockDim.x) w[t]=W1[t];
  for (int t=tid; t<100; t+=blockDim.x) bb[t]=b1[t];
  __syncthreads();
  int i = blockIdx.x*blockDim.x + tid;
  if (i >= N) return;
  float4 self = dxp[i];
  float di = self.x;
  float sx = self.y, sy = self.z, sz = self.w;
  int jb = rowstart[i], je = rowstart[i+1];
  int j = jb;
  for (; j+3 < je; j += 4){
    float4 r0 = dxp[colsrc[j]];
    float4 r1 = dxp[colsrc[j+1]];
    float4 r2 = dxp[colsrc[j+2]];
    float4 r3 = dxp[colsrc[j+3]];
    sx += (r0.y + r1.y) + (r2.y + r3.y);
    sy += (r0.z + r1.z) + (r2.z + r3.z);
    sz += (r0.w + r1.w) + (r2.w + r3.w);
  }
  for (; j < je; ++j){
    float4 r = dxp[colsrc[j]];
    sx += r.y; sy += r.z; sz += r.w;
  }
  sx*=di; sy*=di; sz*=di;
  float* orow = h1s + (size_t)i*100;
#pragma unroll
  for (int f0=0; f0<100; f0+=4){
    float4 o;
    o.x = silu_f(sx*w[f0+0] + sy*w[100+f0+0] + sz*w[200+f0+0] + bb[f0+0]);
    o.y = silu_f(sx*w[f0+1] + sy*w[100+f0+1] + sz*w[200+f0+1] + bb[f0+1]);
    o.z = silu_f(sx*w[f0+2] + sy*w[100+f0+2] + sz*w[200+f0+2] + bb[f0+2]);
    o.w = silu_f(sx*w[f0+3] + sy*w[100+f0+3] + sz*w[200+f0+3] + bb[f0+3]);
    *(float4*)&orow[f0] = o;
  }
}

// ---------- layer 2 aggregation -> bf16 hi/lo planes [N_pad][128] ----------
// HALF-WAVE per node: lanes 0..24 own 4 feats (float4 gather per neighbor);
// lanes 25..31 zero-fill the k=100..127 pad. Split fused here (once/element).
__global__ __launch_bounds__(256) void k_agg2(const float* __restrict__ h1s, const int* __restrict__ rowstart,
                       const int* __restrict__ colsrc, const float* __restrict__ dinv,
                       unsigned short* __restrict__ a2h, unsigned short* __restrict__ a2l, int N){
  int node = blockIdx.x*8 + (threadIdx.x >> 5);
  int lane = threadIdx.x & 31;
  if (node >= N) return;
  if (lane >= 25){
    int ko = 100 + (lane-25)*4;
    ushort4 z = make_ushort4(0,0,0,0);
    *(ushort4*)(a2h + (size_t)node*128 + ko) = z;
    *(ushort4*)(a2l + (size_t)node*128 + ko) = z;
    return;
  }
  float di = dinv[node];
  float4 v = *(const float4*)(h1s + (size_t)node*100 + lane*4);
  float4 acc;
  acc.x = di*v.x; acc.y = di*v.y; acc.z = di*v.z; acc.w = di*v.w;
  int jb = rowstart[node], je = rowstart[node+1];
  int j = jb;
  for (; j+1 < je; j += 2){
    int u0 = colsrc[j];   float w0 = dinv[u0];
    int u1 = colsrc[j+1]; float w1 = dinv[u1];
    float4 r0 = *(const float4*)(h1s + (size_t)u0*100 + lane*4);
    float4 r1 = *(const float4*)(h1s + (size_t)u1*100 + lane*4);
    acc.x += w0*r0.x + w1*r1.x;
    acc.y += w0*r0.y + w1*r1.y;
    acc.z += w0*r0.z + w1*r1.z;
    acc.w += w0*r0.w + w1*r1.w;
  }
  if (j < je){
    int u = colsrc[j]; float wv = dinv[u];
    float4 r = *(const float4*)(h1s + (size_t)u*100 + lane*4);
    acc.x += wv*r.x; acc.y += wv*r.y; acc.z += wv*r.z; acc.w += wv*r.w;
  }
  float o[4] = { di*acc.x, di*acc.y, di*acc.z, di*acc.w };
  ushort4 h4, l4;
  bf16split(o[0], h4.x, l4.x);
  bf16split(o[1], h4.y, l4.y);
  bf16split(o[2], h4.z, l4.z);
  bf16split(o[3], h4.w, l4.w);
  *(ushort4*)(a2h + (size_t)node*128 + lane*4) = h4;
  *(ushort4*)(a2l + (size_t)node*128 + lane*4) = l4;
}

// ---------- layer 2 matmul via split-bf16 MFMA, fragments DIRECT FROM GLOBAL ----------
// h2 = silu(a2 @ W2 + b2); hi*hi + hi*lo + lo*hi (lo*lo ~2^-32 — negligible).
// Block 256 = 4 waves; tile 64n x 32f; wave w: nodes [n0+w*16,+16), 2 f-tiles.
// Lane l: row=l&15, kg=l>>4; A row n0+w*16+row, 16B at k=ks*32+kg*8 — lanes
// {r,r+16,r+32,r+48} fetch 64B contiguous per row (L2/L3-resident planes).
// Pad rows (n>=N) produce garbage only in C-rows the epilogue discards; W pad
// rows are zeroed. No LDS in main loop. C/D map HW-verified (R14 passed).
__global__ __launch_bounds__(256) void k_mm2(const unsigned short* __restrict__ a2h,
                      const unsigned short* __restrict__ a2l,
                      const unsigned short* __restrict__ w2th,
                      const unsigned short* __restrict__ w2tl,
                      const float* __restrict__ b2, const int* __restrict__ batch,
                      float* __restrict__ pooled, int N){
  __shared__ float plL[256];
  int tid = threadIdx.x;
  int l = tid & 63, w = tid >> 6;
  int n0 = blockIdx.x * 64;
  int fb = blockIdx.y;              // f-base = fb*32
  int row = l & 15;
  int kg  = l >> 4;

  const unsigned short* ah_p = a2h + (size_t)(n0 + w*16 + row)*128;
  const unsigned short* al_p = a2l + (size_t)(n0 + w*16 + row)*128;
  int gf0 = fb*32 + row, gf1 = gf0 + 16;
  const unsigned short* wh0_p = w2th + (size_t)gf0*128;
  const unsigned short* wl0_p = w2tl + (size_t)gf0*128;
  const unsigned short* wh1_p = w2th + (size_t)gf1*128;
  const unsigned short* wl1_p = w2tl + (size_t)gf1*128;

  f32x4 acc0 = {0.f,0.f,0.f,0.f};
  f32x4 acc1 = {0.f,0.f,0.f,0.f};
#pragma unroll
  for (int ks = 0; ks < 4; ++ks){
    int ko = ks*32 + kg*8;
    bf16x8 ah  = *(const bf16x8*)(ah_p  + ko);
    bf16x8 al  = *(const bf16x8*)(al_p  + ko);
    bf16x8 wh0 = *(const bf16x8*)(wh0_p + ko);
    bf16x8 wl0 = *(const bf16x8*)(wl0_p + ko);
    bf16x8 wh1 = *(const bf16x8*)(wh1_p + ko);
    bf16x8 wl1 = *(const bf16x8*)(wl1_p + ko);
    acc0 = __builtin_amdgcn_mfma_f32_16x16x32_bf16(ah, wh0, acc0, 0, 0, 0);
    acc0 = __builtin_amdgcn_mfma_f32_16x16x32_bf16(ah, wl0, acc0, 0, 0, 0);
    acc0 = __builtin_amdgcn_mfma_f32_16x16x32_bf16(al, wh0, acc0, 0, 0, 0);
    acc1 = __builtin_amdgcn_mfma_f32_16x16x32_bf16(ah, wh1, acc1, 0, 0, 0);
    acc1 = __builtin_amdgcn_mfma_f32_16x16x32_bf16(ah, wl1, acc1, 0, 0, 0);
    acc1 = __builtin_amdgcn_mfma_f32_16x16x32_bf16(al, wh1, acc1, 0, 0, 0);
  }

  // ---- epilogue: silu + per-block LDS pooled accumulation (8-graph window) ----
  plL[tid] = 0.f;
  __syncthreads();

  int g0 = batch[n0];
#pragma unroll
  for (int ft = 0; ft < 2; ++ft){
    f32x4 a = ft ? acc1 : acc0;
    int fl = ft*16 + row;           // local f in [0,32)
    int gf = fb*32 + fl;
    if (gf < 200){
      float bias = b2[gf];
      float s = 0.f;
      int gprev = -1;
#pragma unroll
      for (int r = 0; r < 4; ++r){
        int node = n0 + w*16 + kg*4 + r;   // C/D row = (l>>4)*4 + r
        if (node < N){
          int g = batch[node];
          if (g != gprev){
            if (gprev >= 0){
              int dg = gprev - g0;
              if (dg < 8) atomicAdd(&plL[dg*32 + fl], s);
              else        atomicAdd(&pooled[(size_t)gprev*200 + gf], s);
            }
            gprev = g; s = 0.f;
          }
          s += silu_f(a[r] + bias);
        }
      }
      if (gprev >= 0){
        int dg = gprev - g0;
        if (dg < 8) atomicAdd(&plL[dg*32 + fl], s);
        else        atomicAdd(&pooled[(size_t)gprev*200 + gf], s);
      }
    }
  }
  __syncthreads();
  {
    float v = plL[tid];
    if (v != 0.f){
      int r = tid >> 5, f = tid & 31;
      int gf = fb*32 + f;
      if (gf < 200) atomicAdd(&pooled[(size_t)(g0+r)*200 + gf], v);
    }
  }
}

// ---------- head: mean finalize + MLP, one block per graph ----------
__global__ __launch_bounds__(256) void k_head(const float* __restrict__ pooled, const int* __restrict__ batch,
                       const float* __restrict__ W3, const float* __restrict__ b3,
                       const float* __restrict__ W4, const float* __restrict__ b4,
                       float* __restrict__ out, int N){
  __shared__ float pl[200];
  __shared__ float h3[100];
  int g = blockIdx.x; int tid = threadIdx.x;
  // lower_bound(batch, g) and lower_bound(batch, g+1) to get node count
  int lo=0, hi=N;
  while (lo<hi){ int m=(lo+hi)>>1; if (batch[m] < g) lo=m+1; else hi=m; }
  int s = lo;
  hi=N;
  while (lo<hi){ int m=(lo+hi)>>1; if (batch[m] < g+1) lo=m+1; else hi=m; }
  int e = lo;
  float inv = (e>s) ? 1.0f/(float)(e-s) : 0.0f;
  if (tid < 200) pl[tid] = pooled[(size_t)g*200 + tid] * inv;
  __syncthreads();
  if (tid < 100){
    float acc = b3[tid];
    for (int k=0;k<200;++k) acc += pl[k]*W3[k*100+tid];
    h3[tid] = silu_f(acc);
  }
  __syncthreads();
  if (tid < WF){
    float p = 0.f;
    if (tid < 100)      p  = h3[tid]     * W4[tid];
    if (tid + 64 < 100) p += h3[tid+64]  * W4[tid+64];
#pragma unroll
    for (int off=32; off; off>>=1) p += __shfl_down(p, off);
    if (tid==0) out[g] = p + b4[0];
  }
}

extern "C" void kernel_launch(void* const* d_in, const int* in_sizes, int n_in,
                              void* d_out, int out_size, void* d_ws, size_t ws_size,
                              hipStream_t stream){
  const float* x  = (const float*)d_in[0];
  const int*   ei = (const int*)  d_in[1];
  const int* batch= (const int*)  d_in[2];
  const float* W1 = (const float*)d_in[4];
  const float* b1 = (const float*)d_in[5];
  const float* W2 = (const float*)d_in[6];
  const float* b2 = (const float*)d_in[7];
  const float* W3 = (const float*)d_in[8];
  const float* b3 = (const float*)d_in[9];
  const float* W4 = (const float*)d_in[10];
  const float* b4 = (const float*)d_in[11];
  float* out = (float*)d_out;

  int N = in_sizes[0]/3;
  int E = in_sizes[1]/2;
  int G = out_size;
  const int* src = ei;
  const int* dst = ei + E;
  int NP = ((N + 63)/64)*64;   // padded rows for mm2 tile overrun

  char* base = (char*)d_ws; size_t off = 0;
  auto alloc = [&](size_t bytes)->void*{
    void* p = base + off;
    off = (off + bytes + 255) & ~(size_t)255;
    return p;
  };
  // zero-init group first (single memset): cnt, pooled
  int*   cnt      = (int*)  alloc((size_t)N*4);
  float* pooled   = (float*)alloc((size_t)G*200*4);
  size_t zbytes   = off;
  int*   rowstart = (int*)  alloc((size_t)(N+1)*4);
  int*   cursor   = (int*)  alloc((size_t)N*4);
  int*   bsum     = (int*)  alloc(4096);
  int*   colsrc   = (int*)  alloc((size_t)E*4);
  float* dinv     = (float*)alloc((size_t)N*4);
  float4* dxp     = (float4*)alloc((size_t)N*16);
  float* h1s      = (float*)alloc((size_t)N*100*4);
  unsigned short* a2h = (unsigned short*)alloc((size_t)NP*128*2);
  unsigned short* a2l = (unsigned short*)alloc((size_t)NP*128*2);
  unsigned short* w2th = (unsigned short*)alloc((size_t)224*128*2);
  unsigned short* w2tl = (unsigned short*)alloc((size_t)224*128*2);
  (void)ws_size; (void)n_in;

  hipMemsetAsync(base, 0, zbytes, stream);
  int gE = (E+255)/256;
  k_count<<<gE,256,0,stream>>>(dst, cnt, E);
  int nb = (N+2047)/2048;
  k_scan1<<<nb,256,0,stream>>>(cnt, rowstart, bsum, N);
  k_scan3<<<(N+255)/256,256,0,stream>>>(bsum, cnt, x, rowstart, cursor, dinv, dxp, N, E, nb);
  k_wconv<<<(224*128+255)/256,256,0,stream>>>(W2, w2th, w2tl);
  k_fill<<<gE,256,0,stream>>>(src, dst, cursor, colsrc, E);
  k_l1<<<(N+255)/256,256,0,stream>>>(dxp, rowstart, colsrc, W1, b1, h1s, N);
  k_agg2<<<(N+7)/8,256,0,stream>>>(h1s, rowstart, colsrc, dinv, a2h, a2l, N);
  dim3 gmm((N+63)/64, 7);
  k_mm2<<<gmm,256,0,stream>>>(a2h, a2l, w2th, w2tl, b2, batch, pooled, N);
  k_head<<<G,256,0,stream>>>(pooled, batch, W3, b3, W4, b4, out, N);
}